// Round 6
// baseline (36.103 us; speedup 1.0000x reference)
//
#include <hip/hip_runtime.h>
#include <math.h>
#include <float.h>

#define B 32
#define N 2048
#define EPS 1e-6f

typedef _Float16 half4_t __attribute__((ext_vector_type(4)));
typedef _Float16 half8_t __attribute__((ext_vector_type(8)));
typedef float f32x4 __attribute__((ext_vector_type(4)));

// ws layout (halves / bytes):
//   predA @ 0        : 32*2048*16 f16 = 2 MB  (pred expanded as query rows)
//   tgtA  @ 2 MB     : target as query rows
//   predB @ 4 MB     : pred expanded as ref cols
//   tgtB  @ 6 MB     : target as ref cols
//   partial @ 8 MB   : 2048 f32 per-wave partial sums

// Expand each point into MFMA A-row form and B-col form with 2-term fp16 splits.
// d^2(q,r) = sum_k A_k(q) * B_k(r):
//  k0..2: x*(−2rx) via (xh,xh,xl)·(uxh,uxl,uxh);  k3..5: y-part;
//  k6..7: |q|^2 via (qqh,qql)·(1,1);  k8..9: |r|^2 via (1,1)·(rrh,rrl); k10..15: 0
__global__ __launch_bounds__(256) void preproc_kernel(
    const float* __restrict__ pred, const float* __restrict__ target,
    _Float16* __restrict__ predA, _Float16* __restrict__ tgtA,
    _Float16* __restrict__ predB, _Float16* __restrict__ tgtB) {
  const int g = blockIdx.x * 256 + threadIdx.x;   // 0..131071
  const int which = g >> 16;                      // 0: pred, 1: target
  const int idx = g & 65535;                      // b*2048 + i
  const float2 p = ((const float2*)(which ? target : pred))[idx];

  const float qq = fmaf(p.x, p.x, p.y * p.y);
  const _Float16 xh = (_Float16)p.x;  const _Float16 xl = (_Float16)(p.x - (float)xh);
  const _Float16 yh = (_Float16)p.y;  const _Float16 yl = (_Float16)(p.y - (float)yh);
  const _Float16 qh = (_Float16)qq;   const _Float16 ql = (_Float16)(qq - (float)qh);
  const float ux = -2.f * p.x, uy = -2.f * p.y;
  const _Float16 uxh = (_Float16)ux;  const _Float16 uxl = (_Float16)(ux - (float)uxh);
  const _Float16 uyh = (_Float16)uy;  const _Float16 uyl = (_Float16)(uy - (float)uyh);
  const _Float16 one = (_Float16)1.f, zer = (_Float16)0.f;

  _Float16* A  = (which ? tgtA : predA) + (size_t)idx * 16;
  _Float16* Bp = (which ? tgtB : predB) + (size_t)idx * 16;
  half8_t a0 = {xh, xh, xl, yh, yh, yl, qh, ql};
  half8_t a1 = {one, one, zer, zer, zer, zer, zer, zer};
  half8_t b0 = {uxh, uxl, uxh, uyh, uyl, uyh, one, one};
  half8_t b1 = {qh, ql, zer, zer, zer, zer, zer, zer};
  *(half8_t*)A        = a0;
  *(half8_t*)(A + 8)  = a1;
  *(half8_t*)Bp       = b0;
  *(half8_t*)(Bp + 8) = b1;
}

// One block: 256 query rows (panel) x ALL 2048 ref cols for one (dir, b).
// 4 waves; wave w owns 64 rows = 4 MFMA row-tiles of 16. B panel staged in LDS (64 KB).
// mfma_f32_16x16x16f16: A lane l: row=l%16, k=(l/16)*4+e; B lane l: col=l%16, same k.
// D lane l: col=l%16, row=(l/16)*4+reg.  (any transpose confusion self-cancels
// across the two directions — see launch grid covering dir=0 and dir=1)
__global__ __launch_bounds__(256) void gemm_min_kernel(
    const _Float16* __restrict__ predA, const _Float16* __restrict__ tgtA,
    const _Float16* __restrict__ predB, const _Float16* __restrict__ tgtB,
    float* __restrict__ partial) {
  const int panel = blockIdx.x;   // 0..7
  const int db    = blockIdx.y;   // 0..63
  const int dir   = db >> 5;
  const int b     = db & 31;

  const _Float16* Aset = (dir ? tgtA : predA) + (size_t)b * N * 16;
  const _Float16* Bset = (dir ? predB : tgtB) + (size_t)b * N * 16;

  __shared__ _Float16 ldsB[N * 16];   // 64 KB

  // stage B panel: 64 KB = 16 iters * 256 thr * 16 B
  {
    const uint4* src = (const uint4*)Bset;
    uint4* dst = (uint4*)ldsB;
#pragma unroll
    for (int it = 0; it < 16; ++it)
      dst[it * 256 + threadIdx.x] = src[it * 256 + threadIdx.x];
  }

  const int lane = threadIdx.x & 63;
  const int w    = threadIdx.x >> 6;
  const int rowbase = panel * 256 + w * 64;

  // A fragments for 4 row-tiles, straight from global (reused across all cols)
  half4_t afrag[4];
#pragma unroll
  for (int t = 0; t < 4; ++t) {
    const _Float16* ap =
        Aset + (size_t)(rowbase + t * 16 + (lane & 15)) * 16 + (lane >> 4) * 4;
    afrag[t] = *(const half4_t*)ap;
  }

  __syncthreads();

  const f32x4 zero4 = {0.f, 0.f, 0.f, 0.f};
  float acc[4][4];
#pragma unroll
  for (int t = 0; t < 4; ++t)
#pragma unroll
    for (int k = 0; k < 4; ++k) acc[t][k] = FLT_MAX;

#pragma unroll 2
  for (int ct = 0; ct < N / 16; ++ct) {
    const _Float16* bp =
        ldsB + (size_t)(ct * 16 + (lane & 15)) * 16 + (lane >> 4) * 4;
    half4_t bfrag = *(const half4_t*)bp;
#pragma unroll
    for (int t = 0; t < 4; ++t) {
      f32x4 d = __builtin_amdgcn_mfma_f32_16x16x16f16(afrag[t], bfrag, zero4, 0, 0, 0);
      acc[t][0] = fminf(acc[t][0], d[0]);
      acc[t][1] = fminf(acc[t][1], d[1]);
      acc[t][2] = fminf(acc[t][2], d[2]);
      acc[t][3] = fminf(acc[t][3], d[3]);
    }
  }

  // butterfly min over the 16 lanes (cols) sharing the same row set
#pragma unroll
  for (int t = 0; t < 4; ++t)
#pragma unroll
    for (int k = 0; k < 4; ++k) {
      float v = acc[t][k];
      v = fminf(v, __shfl_xor(v, 1, 64));
      v = fminf(v, __shfl_xor(v, 2, 64));
      v = fminf(v, __shfl_xor(v, 4, 64));
      v = fminf(v, __shfl_xor(v, 8, 64));
      acc[t][k] = v;
    }

  // each lane-group (lane>>4) holds mins for 16 distinct rows: sum sqrt
  float s = 0.f;
#pragma unroll
  for (int t = 0; t < 4; ++t)
#pragma unroll
    for (int k = 0; k < 4; ++k)
      s += sqrtf(fmaxf(acc[t][k], 0.f) + EPS);
  // combine the 4 lane-groups (distinct rows each)
  s += __shfl_xor(s, 16, 64);
  s += __shfl_xor(s, 32, 64);

  if (lane == 0) partial[((size_t)db * 8 + panel) * 4 + w] = s;
}

// Final: reduce 2048 per-wave partials, scale, write scalar.
__global__ __launch_bounds__(512) void final_kernel(
    const float* __restrict__ partial, float* __restrict__ out) {
  float v = 0.f;
#pragma unroll
  for (int k = 0; k < 4; ++k) v += partial[k * 512 + threadIdx.x];
#pragma unroll
  for (int off = 32; off > 0; off >>= 1)
    v += __shfl_down(v, off, 64);
  __shared__ float wsum[8];
  if ((threadIdx.x & 63) == 0) wsum[threadIdx.x >> 6] = v;
  __syncthreads();
  if (threadIdx.x == 0) {
    float s = 0.f;
#pragma unroll
    for (int i = 0; i < 8; ++i) s += wsum[i];
    out[0] = s * (1.0f / (float)(B * N));
  }
}

extern "C" void kernel_launch(void* const* d_in, const int* in_sizes, int n_in,
                              void* d_out, int out_size, void* d_ws, size_t ws_size,
                              hipStream_t stream) {
  const float* pred   = (const float*)d_in[0];
  const float* target = (const float*)d_in[1];
  float* out = (float*)d_out;

  const size_t SET = (size_t)B * N * 16;   // halves per expanded set
  _Float16* predA = (_Float16*)d_ws;
  _Float16* tgtA  = predA + SET;
  _Float16* predB = tgtA + SET;
  _Float16* tgtB  = predB + SET;
  float* partial  = (float*)(tgtB + SET);  // 2048 floats @ 8 MB

  preproc_kernel<<<512, 256, 0, stream>>>(pred, target, predA, tgtA, predB, tgtB);
  dim3 grid(8, 64);
  gemm_min_kernel<<<grid, 256, 0, stream>>>(predA, tgtA, predB, tgtB, partial);
  final_kernel<<<1, 512, 0, stream>>>(partial, out);
}

// Round 7
// 27.446 us; speedup vs baseline: 1.3154x; 1.3154x over previous
//
#include <hip/hip_runtime.h>
#include <math.h>
#include <float.h>

#define B 32
#define N 2048
#define EPS 1e-6f
#define CHUNK 512             // ref cols per block
#define NCHUNK (N / CHUNK)    // 4
#define NPANEL 8              // 256 query rows per block
#define NQ_TOTAL (2 * B * N)  // 131072

typedef _Float16 half4_t __attribute__((ext_vector_type(4)));
typedef _Float16 half8_t __attribute__((ext_vector_type(8)));
typedef float f32x4 __attribute__((ext_vector_type(4)));

// d^2(q,r) = sum_k A_k(q)*B_k(r), K=10 of 16 (fp16 2-term splits, fp32 accum):
//  A = [xh,xh,xl,yh, yh,yl,qqh,qql, 1,1,0,0, 0,0,0,0]
//  B = [uxh,uxl,uxh,uyh, uyl,uyh,1,1, rrh,rrl,0,0, 0,0,0,0]   (u = -2r)
// Encodings + mfma lane layout verified by R6 (absmax 0.0).

// Stage 1: 256 rows x 512-col chunk per block; MFMA 16x16x16f16; per-row
// chunk-min written to pmin. A-frags built in registers; B converted during
// LDS staging (no preproc kernel, forms never touch HBM).
__global__ __launch_bounds__(256) void gemm_min_kernel(
    const float* __restrict__ pred, const float* __restrict__ target,
    float* __restrict__ pmin) {
  const int panel = blockIdx.x;   // 0..7
  const int c     = blockIdx.y;   // 0..3
  const int db    = blockIdx.z;   // 0..63
  const int dir   = db >> 5;
  const int b     = db & 31;

  const float* qraw = (dir ? target : pred) + (size_t)b * N * 2;
  const float* rraw = (dir ? pred : target) + (size_t)b * N * 2;

  __shared__ _Float16 ldsB[CHUNK * 16];   // 16 KB

  // stage+convert B chunk: thread t -> cols 2t, 2t+1
  {
    const float4 rv = ((const float4*)rraw)[c * (CHUNK / 2) + threadIdx.x];
    const _Float16 one = (_Float16)1.f, zer = (_Float16)0.f;
#pragma unroll
    for (int pi = 0; pi < 2; ++pi) {
      const float x = pi ? rv.z : rv.x;
      const float y = pi ? rv.w : rv.y;
      const float ux = -2.f * x, uy = -2.f * y;
      const float rr = fmaf(x, x, y * y);
      const _Float16 uxh = (_Float16)ux; const _Float16 uxl = (_Float16)(ux - (float)uxh);
      const _Float16 uyh = (_Float16)uy; const _Float16 uyl = (_Float16)(uy - (float)uyh);
      const _Float16 rrh = (_Float16)rr; const _Float16 rrl = (_Float16)(rr - (float)rrh);
      half8_t b0 = {uxh, uxl, uxh, uyh, uyl, uyh, one, one};
      half8_t b1 = {rrh, rrl, zer, zer, zer, zer, zer, zer};
      half8_t* dst = (half8_t*)(ldsB + (size_t)(2 * threadIdx.x + pi) * 16);
      dst[0] = b0;
      dst[1] = b1;
    }
  }

  const int lane = threadIdx.x & 63;
  const int w    = threadIdx.x >> 6;
  const int kg   = lane >> 4;
  const int cl   = lane & 15;
  const int rowbase = panel * 256 + w * 64;

  // A-frags in registers: lane holds k-slice kg*4..kg*4+3 of its row's A-vector
  half4_t afrag[4];
#pragma unroll
  for (int t = 0; t < 4; ++t) {
    const float2 qp = ((const float2*)qraw)[rowbase + t * 16 + cl];
    const float qq = fmaf(qp.x, qp.x, qp.y * qp.y);
    const _Float16 xh = (_Float16)qp.x; const _Float16 xl = (_Float16)(qp.x - (float)xh);
    const _Float16 yh = (_Float16)qp.y; const _Float16 yl = (_Float16)(qp.y - (float)yh);
    const _Float16 qh = (_Float16)qq;   const _Float16 ql = (_Float16)(qq - (float)qh);
    const _Float16 one = (_Float16)1.f, zer = (_Float16)0.f;
    half4_t af;
    if (kg == 0)      af = half4_t{xh, xh, xl, yh};
    else if (kg == 1) af = half4_t{yh, yl, qh, ql};
    else if (kg == 2) af = half4_t{one, one, zer, zer};
    else              af = half4_t{zer, zer, zer, zer};
    afrag[t] = af;
  }

  __syncthreads();

  const f32x4 zero4 = {0.f, 0.f, 0.f, 0.f};
  float acc[4][4];
#pragma unroll
  for (int t = 0; t < 4; ++t)
#pragma unroll
    for (int k = 0; k < 4; ++k) acc[t][k] = FLT_MAX;

#pragma unroll 4
  for (int ct = 0; ct < CHUNK / 16; ++ct) {   // 32 iters
    half4_t bfrag = *(const half4_t*)(ldsB + (size_t)(ct * 16 + cl) * 16 + kg * 4);
#pragma unroll
    for (int t = 0; t < 4; ++t) {
      f32x4 d = __builtin_amdgcn_mfma_f32_16x16x16f16(afrag[t], bfrag, zero4, 0, 0, 0);
      acc[t][0] = fminf(acc[t][0], d[0]);
      acc[t][1] = fminf(acc[t][1], d[1]);
      acc[t][2] = fminf(acc[t][2], d[2]);
      acc[t][3] = fminf(acc[t][3], d[3]);
    }
  }

  // min over the 16 col-lanes within each kg group
#pragma unroll
  for (int t = 0; t < 4; ++t)
#pragma unroll
    for (int k = 0; k < 4; ++k) {
      float v = acc[t][k];
      v = fminf(v, __shfl_xor(v, 1, 64));
      v = fminf(v, __shfl_xor(v, 2, 64));
      v = fminf(v, __shfl_xor(v, 4, 64));
      v = fminf(v, __shfl_xor(v, 8, 64));
      acc[t][k] = v;
    }

  // static-index select: lane cl = t*4+k owns row t*16 + kg*4 + k
  float val = acc[0][0];
#pragma unroll
  for (int t = 0; t < 4; ++t)
#pragma unroll
    for (int k = 0; k < 4; ++k)
      if (cl == t * 4 + k) val = acc[t][k];
  const int row_local = (cl >> 2) * 16 + kg * 4 + (cl & 3);
  pmin[((size_t)db * NCHUNK + c) * N + rowbase + row_local] = val;
}

// Stage 2 (R4-proven): per-query min over 4 chunks, sqrt, block-sum.
__global__ __launch_bounds__(256) void chamfer_combine_kernel(
    const float* __restrict__ pmin, float* __restrict__ partial2) {
  const int g  = blockIdx.x * 256 + threadIdx.x;  // 0..131071
  const int db = g >> 11;
  const int qi = g & 2047;
  const float* p = pmin + (size_t)db * NCHUNK * N + qi;
  float v = fminf(fminf(p[0], p[N]), fminf(p[2 * N], p[3 * N]));
  float s = sqrtf(fmaxf(v, 0.f) + EPS);
#pragma unroll
  for (int off = 32; off > 0; off >>= 1)
    s += __shfl_down(s, off, 64);
  __shared__ float wsum[4];
  if ((threadIdx.x & 63) == 0) wsum[threadIdx.x >> 6] = s;
  __syncthreads();
  if (threadIdx.x == 0)
    partial2[blockIdx.x] = wsum[0] + wsum[1] + wsum[2] + wsum[3];
}

// Stage 3 (R4-proven): final 512-way reduce, scale, write scalar.
__global__ __launch_bounds__(512) void chamfer_final_kernel(
    const float* __restrict__ partial2, float* __restrict__ out) {
  float v = partial2[threadIdx.x];
#pragma unroll
  for (int off = 32; off > 0; off >>= 1)
    v += __shfl_down(v, off, 64);
  __shared__ float wsum[8];
  if ((threadIdx.x & 63) == 0) wsum[threadIdx.x >> 6] = v;
  __syncthreads();
  if (threadIdx.x == 0) {
    float s = 0.f;
#pragma unroll
    for (int i = 0; i < 8; ++i) s += wsum[i];
    out[0] = s * (1.0f / (float)(B * N));
  }
}

extern "C" void kernel_launch(void* const* d_in, const int* in_sizes, int n_in,
                              void* d_out, int out_size, void* d_ws, size_t ws_size,
                              hipStream_t stream) {
  const float* pred   = (const float*)d_in[0];
  const float* target = (const float*)d_in[1];
  float* out = (float*)d_out;

  float* pmin     = (float*)d_ws;                               // 524288 f32 (2 MB)
  float* partial2 = (float*)d_ws + (size_t)2 * B * NCHUNK * N;  // 512 f32

  dim3 grid1(NPANEL, NCHUNK, 2 * B);   // (8,4,64) = 2048 blocks, 8/CU
  gemm_min_kernel<<<grid1, 256, 0, stream>>>(pred, target, pmin);
  chamfer_combine_kernel<<<NQ_TOTAL / 256, 256, 0, stream>>>(pmin, partial2);
  chamfer_final_kernel<<<1, 512, 0, stream>>>(partial2, out);
}

// Round 8
// 26.328 us; speedup vs baseline: 1.3713x; 1.0425x over previous
//
#include <hip/hip_runtime.h>
#include <math.h>
#include <float.h>

#define B 32
#define N 2048
#define EPS 1e-6f

// Stage 1 (fused): 2048 blocks x 128 threads. Block = 64 queries (panel) x ALL
// 2048 refs for one (dir,b). Refs staged+expanded through LDS in 4 chunks of
// 512. Thread (r=tid&31, s=tid>>5): queries {panel*64+r, panel*64+32+r}(Q=2),
// ref-split s (128 refs per chunk). Expanded form (R3/R4-proven):
// t = |r|^2 - 2 q.r, min over t, add |q|^2 once at the end.
// LDS group g (4 refs): X4@(48g+16s'), Y4@+16, C4@+32, s'=g>>5 pad keeps the
// 4 splits' broadcast reads on disjoint banks (offset 1552B = bank shift 4).
__global__ __launch_bounds__(128) void chamfer_fused_kernel(
    const float* __restrict__ pred, const float* __restrict__ target,
    float* __restrict__ partial) {
  const int panel = blockIdx.x;   // 0..31
  const int db    = blockIdx.y;   // 0..63
  const int dir   = db >> 5;
  const int b     = db & 31;

  const float* qraw = (dir ? target : pred) + (size_t)b * N * 2;
  const float* rraw = (dir ? pred : target) + (size_t)b * N * 2;

  __shared__ float Lf[1552];   // 6208 B: 128 groups * 12 floats + 4 split pads

  const int r = threadIdx.x & 31;
  const int s = threadIdx.x >> 5;

  const float2 qp0 = ((const float2*)qraw)[panel * 64 + r];
  const float2 qp1 = ((const float2*)qraw)[panel * 64 + 32 + r];
  const float qq0 = fmaf(qp0.x, qp0.x, qp0.y * qp0.y);
  const float qq1 = fmaf(qp1.x, qp1.x, qp1.y * qp1.y);

  float a00 = FLT_MAX, a01 = FLT_MAX;   // two chains, query 0
  float a10 = FLT_MAX, a11 = FLT_MAX;   // two chains, query 1

  for (int c = 0; c < 4; ++c) {
    if (c) __syncthreads();   // protect LDS overwrite vs previous chunk reads
    {
      // stage+expand: thread owns group g=tid (refs 4g..4g+3 of this chunk)
      const float4* r4 = (const float4*)rraw + c * 256;
      float4 rv0 = r4[2 * threadIdx.x];
      float4 rv1 = r4[2 * threadIdx.x + 1];
      const int off = threadIdx.x * 12 + (threadIdx.x >> 5) * 4;
      *(float4*)(Lf + off) =
          make_float4(-2.f * rv0.x, -2.f * rv0.z, -2.f * rv1.x, -2.f * rv1.z);
      *(float4*)(Lf + off + 4) =
          make_float4(-2.f * rv0.y, -2.f * rv0.w, -2.f * rv1.y, -2.f * rv1.w);
      *(float4*)(Lf + off + 8) = make_float4(
          fmaf(rv0.x, rv0.x, rv0.y * rv0.y), fmaf(rv0.z, rv0.z, rv0.w * rv0.w),
          fmaf(rv1.x, rv1.x, rv1.y * rv1.y), fmaf(rv1.z, rv1.z, rv1.w * rv1.w));
    }
    __syncthreads();

    const int sbase = s * (32 * 12) + s * 4;
#pragma unroll 8
    for (int jj = 0; jj < 32; ++jj) {
      const int off = sbase + jj * 12;
      float4 X = *(const float4*)(Lf + off);
      float4 Y = *(const float4*)(Lf + off + 4);
      float4 C = *(const float4*)(Lf + off + 8);
      float d0 = fmaf(X.x, qp0.x, fmaf(Y.x, qp0.y, C.x));
      float d1 = fmaf(X.y, qp0.x, fmaf(Y.y, qp0.y, C.y));
      float d2 = fmaf(X.z, qp0.x, fmaf(Y.z, qp0.y, C.z));
      float d3 = fmaf(X.w, qp0.x, fmaf(Y.w, qp0.y, C.w));
      a00 = fminf(fminf(a00, d0), d1);
      a01 = fminf(fminf(a01, d2), d3);
      float e0 = fmaf(X.x, qp1.x, fmaf(Y.x, qp1.y, C.x));
      float e1 = fmaf(X.y, qp1.x, fmaf(Y.y, qp1.y, C.y));
      float e2 = fmaf(X.z, qp1.x, fmaf(Y.z, qp1.y, C.z));
      float e3 = fmaf(X.w, qp1.x, fmaf(Y.w, qp1.y, C.w));
      a10 = fminf(fminf(a10, e0), e1);
      a11 = fminf(fminf(a11, e2), e3);
    }
  }

  // cross-split combine via LDS (4 splits per query row)
  __syncthreads();
  Lf[s * 32 + r]       = fminf(a00, a01);
  Lf[128 + s * 32 + r] = fminf(a10, a11);
  __syncthreads();
  if (threadIdx.x < 32) {
    float v0 = fminf(fminf(Lf[r], Lf[32 + r]), fminf(Lf[64 + r], Lf[96 + r]));
    float v1 = fminf(fminf(Lf[128 + r], Lf[160 + r]),
                     fminf(Lf[192 + r], Lf[224 + r]));
    float sthr = sqrtf(fmaxf(v0 + qq0, 0.f) + EPS) +
                 sqrtf(fmaxf(v1 + qq1, 0.f) + EPS);
#pragma unroll
    for (int k = 16; k > 0; k >>= 1)
      sthr += __shfl_down(sthr, k, 64);
    if (r == 0) partial[db * 32 + panel] = sthr;
  }
}

// Final: one wave sums 2048 partials (8 KB), scales, writes scalar.
__global__ __launch_bounds__(64) void chamfer_final_kernel(
    const float* __restrict__ partial, float* __restrict__ out) {
  float v = 0.f;
#pragma unroll
  for (int k = 0; k < 32; ++k) v += partial[k * 64 + threadIdx.x];
#pragma unroll
  for (int k = 32; k > 0; k >>= 1)
    v += __shfl_down(v, k, 64);
  if (threadIdx.x == 0) out[0] = v * (1.0f / 65536.f);  // 1/(B*N)
}

extern "C" void kernel_launch(void* const* d_in, const int* in_sizes, int n_in,
                              void* d_out, int out_size, void* d_ws, size_t ws_size,
                              hipStream_t stream) {
  const float* pred   = (const float*)d_in[0];
  const float* target = (const float*)d_in[1];
  float* out = (float*)d_out;
  float* partial = (float*)d_ws;   // 2048 floats

  dim3 grid1(32, 64);   // 2048 blocks, 8/CU, 16 waves/CU
  chamfer_fused_kernel<<<grid1, 128, 0, stream>>>(pred, target, partial);
  chamfer_final_kernel<<<1, 64, 0, stream>>>(partial, out);
}